// Round 23
// baseline (131.285 us; speedup 1.0000x reference)
//
#include <hip/hip_runtime.h>
#include <stdint.h>

#define IN_F   4096
#define OUT_F  11008
#define BATCH  8
#define RPW    2          // output rows per wave
#define WAVES  4          // waves per block
#define RPB    (RPW*WAVES)
#define CHUNK  1024       // i-values per chunk = 4 KB/row (64 lines, 1 per lane)

__device__ __forceinline__ float qins_decode(int code, int sgn, float d0, float d1) {
    // |w| = exp2(d0 + code*d1); sign bit straight from the int32 sign (+1 / -1)
    const float e = __builtin_amdgcn_exp2f(fmaf((float)code, d1, d0));
    const uint32_t m = ((uint32_t)sgn) & 0x80000000u;
    return __uint_as_float(__float_as_uint(e) ^ m);
}

// Line-strided streaming kernel: within each 4 KB chunk, lane l owns cache
// line l (ints 16l..16l+15). Every vector load instruction touches 64
// DISTINCT 64B lines -> 4 KB in flight per vmcnt slot (4x the coalesced
// pattern; R4 measured 2.83 TB/s with this line-per-lane shape). Dot-product
// lane<->i permutation is free; x uses the same mapping.
__global__ __launch_bounds__(WAVES*64, 4)
void qins_linear_kernel(const float* __restrict__ x,
                        const int*   __restrict__ stored,
                        const int*   __restrict__ sign,
                        const float* __restrict__ log_min,
                        const float* __restrict__ log_max,
                        const float* __restrict__ bias,
                        float* __restrict__ out)
{
    const int lane = threadIdx.x & 63;
    const int wave = threadIdx.x >> 6;
    const int o0   = blockIdx.x * RPB + wave * RPW;

    const float lmin = log_min[0];
    const float lmax = log_max[0];
    const float L2E  = 1.44269504088896340736f;
    // log2(|w|) = d0 + code*d1
    const float d1 = -(lmax - lmin) * (L2E / 254.0f);
    const float d0 = (lmin + (lmax - lmin) * (255.0f / 254.0f)) * L2E;

    float acc[RPW][BATCH];
#pragma unroll
    for (int r = 0; r < RPW; ++r)
#pragma unroll
        for (int b = 0; b < BATCH; ++b) acc[r][b] = 0.0f;

    const int lb    = lane * 16;                 // this lane's line offset (ints)
    const int row0  = (o0 + 0) * IN_F + lb;
    const int row1  = (o0 + 1) * IN_F + lb;

#pragma unroll 1
    for (int c = 0; c < IN_F; c += CHUNK) {
#pragma unroll
        for (int j = 0; j < 4; ++j) {
            const int ip = c + 4 * j;            // + lane line base below
            const int4 c0 = *reinterpret_cast<const int4*>(stored + row0 + ip);
            const int4 c1 = *reinterpret_cast<const int4*>(stored + row1 + ip);
            const int4 g0 = *reinterpret_cast<const int4*>(sign + row0 + ip);
            const int4 g1 = *reinterpret_cast<const int4*>(sign + row1 + ip);

            const float w00 = qins_decode(c0.x, g0.x, d0, d1);
            const float w01 = qins_decode(c0.y, g0.y, d0, d1);
            const float w02 = qins_decode(c0.z, g0.z, d0, d1);
            const float w03 = qins_decode(c0.w, g0.w, d0, d1);
            const float w10 = qins_decode(c1.x, g1.x, d0, d1);
            const float w11 = qins_decode(c1.y, g1.y, d0, d1);
            const float w12 = qins_decode(c1.z, g1.z, d0, d1);
            const float w13 = qins_decode(c1.w, g1.w, d0, d1);

#pragma unroll
            for (int b = 0; b < BATCH; ++b) {
                const float4 t = *reinterpret_cast<const float4*>(
                    x + b * IN_F + ip + lb);
                float a0 = acc[0][b];
                float a1 = acc[1][b];
                a0 = fmaf(w00, t.x, a0); a1 = fmaf(w10, t.x, a1);
                a0 = fmaf(w01, t.y, a0); a1 = fmaf(w11, t.y, a1);
                a0 = fmaf(w02, t.z, a0); a1 = fmaf(w12, t.z, a1);
                a0 = fmaf(w03, t.w, a0); a1 = fmaf(w13, t.w, a1);
                acc[0][b] = a0;
                acc[1][b] = a1;
            }
        }
    }

    // butterfly reduction of the 16 (row,batch) partials across the wave
#pragma unroll
    for (int r = 0; r < RPW; ++r)
#pragma unroll
        for (int b = 0; b < BATCH; ++b) {
            float v = acc[r][b];
#pragma unroll
            for (int s = 32; s >= 1; s >>= 1)
                v += __shfl_xor(v, s, 64);
            acc[r][b] = v;
        }

    if (lane == 0) {
#pragma unroll
        for (int r = 0; r < RPW; ++r) {
            const float bv = bias[o0 + r];
#pragma unroll
            for (int b = 0; b < BATCH; ++b)
                out[(size_t)b * OUT_F + o0 + r] = acc[r][b] + bv;
        }
    }
}

extern "C" void kernel_launch(void* const* d_in, const int* in_sizes, int n_in,
                              void* d_out, int out_size, void* d_ws, size_t ws_size,
                              hipStream_t stream)
{
    const float* x      = (const float*)d_in[0];
    const int*   stored = (const int*)d_in[1];
    const int*   sign   = (const int*)d_in[2];
    const float* lmin   = (const float*)d_in[3];
    const float* lmax   = (const float*)d_in[4];
    const float* bias   = (const float*)d_in[5];
    float* out = (float*)d_out;

    dim3 grid(OUT_F / RPB), block(WAVES * 64);
    qins_linear_kernel<<<grid, block, 0, stream>>>(x, stored, sign, lmin, lmax, bias, out);
}

// Round 24
// 92.195 us; speedup vs baseline: 1.4240x; 1.4240x over previous
//
#include <hip/hip_runtime.h>
#include <stdint.h>

#define IN_F   4096
#define OUT_F  11008
#define BATCH  8
#define WAVES  4
#define RPB    64                 // rows per block
#define NS     8                  // split-K slices
#define SLICE  (IN_F/NS)          // 512 i per block
#define PHI    32                 // i per phase
#define NPH    (SLICE/PHI)        // 16 phases
#define NSLOT  3                  // ring slots
#define SLOTI  4096               // ints per slot: stored[8][64][4] | sign[8][64][4]
#define SLOTB  (SLOTI*4)          // 16384 B
#define XOFFI  (NSLOT*SLOTI)      // 12288 ints
#define XOFFB  (XOFFI*4)          // 49152 B
#define XROW   520                // padded x row stride (ints)
#define RGRPS  (OUT_F/RPB)        // 172

typedef __attribute__((address_space(1))) const int* gas_t;
typedef __attribute__((address_space(3))) int* las_t;
typedef int i32x4 __attribute__((ext_vector_type(4)));

// async global->LDS DMA, 16 B/lane, PER-LANE global address (m104):
// lane l sources row l -> ONE instruction touches 64 distinct cache lines.
#define DMA16(gsrc, ldst) \
    __builtin_amdgcn_global_load_lds((gas_t)(gsrc), (las_t)(ldst), 16, 0, 0)

#define SBAR() __builtin_amdgcn_sched_barrier(0)
#define VWAIT(N)                                                             \
    do {                                                                     \
        asm volatile("s_waitcnt vmcnt(" #N ")" ::: "memory");                \
        SBAR();                                                              \
    } while (0)
// compiler-opaque LDS read (R18-proven: no auto vmcnt(0) drain)
#define DSR(dst, a, OFF)                                                     \
    asm volatile("ds_read_b128 %0, %1 offset:" #OFF : "=v"(dst) : "v"(a))
#define LGKM0()                                                              \
    do {                                                                     \
        asm volatile("s_waitcnt lgkmcnt(0)" ::: "memory");                   \
        SBAR();                                                              \
    } while (0)

__device__ __forceinline__ float qins_decode(int code, int sgn, float d0, float d1) {
    // |w| = exp2(d0 + code*d1); sign bit straight from the int32 sign (+1 / -1)
    const float e = __builtin_amdgcn_exp2f(fmaf((float)code, d1, d0));
    const uint32_t m = ((uint32_t)sgn) & 0x80000000u;
    return __uint_as_float(__float_as_uint(e) ^ m);
}

// decode 4 weights from one stored/sign vec, FMA into the lane's 2 batch accs
#define STEP4(CS, CG, XA, XB)                                                \
    do {                                                                     \
        float wt;                                                            \
        wt = qins_decode((CS).x, (CG).x, d0, d1);                            \
        acc0 = fmaf(wt, __int_as_float((XA).x), acc0);                       \
        acc1 = fmaf(wt, __int_as_float((XB).x), acc1);                       \
        wt = qins_decode((CS).y, (CG).y, d0, d1);                            \
        acc0 = fmaf(wt, __int_as_float((XA).y), acc0);                       \
        acc1 = fmaf(wt, __int_as_float((XB).y), acc1);                       \
        wt = qins_decode((CS).z, (CG).z, d0, d1);                            \
        acc0 = fmaf(wt, __int_as_float((XA).z), acc0);                       \
        acc1 = fmaf(wt, __int_as_float((XB).z), acc1);                       \
        wt = qins_decode((CS).w, (CG).w, d0, d1);                            \
        acc0 = fmaf(wt, __int_as_float((XA).w), acc0);                       \
        acc1 = fmaf(wt, __int_as_float((XB).w), acc1);                       \
    } while (0)

// out[b][o] = bias[o]  (out not re-poisoned between replays; re-init each call)
__global__ void qins_init(const float* __restrict__ bias, float* __restrict__ out)
{
    const int o = blockIdx.x * 256 + threadIdx.x;
    const float bv = bias[o];
#pragma unroll
    for (int b = 0; b < BATCH; ++b)
        out[(size_t)b * OUT_F + o] = bv;
}

__global__ __launch_bounds__(256, 2)
void qins_main(const float* __restrict__ x,
               const int* __restrict__ stored,
               const int* __restrict__ sign,
               const float* __restrict__ log_min,
               const float* __restrict__ log_max,
               float* __restrict__ out)
{
    // ring slot t: stored j=0..7 at t*4096 + j*256 + lane*4 ; sign at +2048
    // x region:   batch b at XOFFI + b*520 + i   (pad kills bank conflicts)
    __shared__ int lds[XOFFI + BATCH * XROW];

    const int tid  = threadIdx.x;
    const int lane = tid & 63;
    const int wave = tid >> 6;
    const int rg   = blockIdx.x % RGRPS;
    const int s    = blockIdx.x / RGRPS;
    const int o0   = rg * RPB;
    const int i0   = s * SLICE;

    const float lmin = log_min[0];
    const float lmax = log_max[0];
    const float L2E  = 1.44269504088896340736f;
    // log2(|w|) = d0 + code*d1
    const float d1 = -(lmax - lmin) * (L2E / 254.0f);
    const float d0 = (lmin + (lmax - lmin) * (255.0f / 254.0f)) * L2E;

    // ---- x slice staged once: 8 batches x 512 ints, int2 per thread per batch
#pragma unroll
    for (int b = 0; b < BATCH; ++b) {
        const int2 v = *reinterpret_cast<const int2*>(
            (const int*)x + b * IN_F + i0 + 2 * tid);
        *reinterpret_cast<int2*>(&lds[XOFFI + b * XROW + 2 * tid]) = v;
    }
    __syncthreads();

    // per-lane scattered DMA sources: lane l -> row o0+l
    const int* gsl = stored + (size_t)(o0 + lane) * IN_F + i0;
    const int* ggl = sign   + (size_t)(o0 + lane) * IN_F + i0;

    // wave w issues sub-DMAs j = 2w, 2w+1 for both streams (4 DMAs/phase/wave)
#define ISSUE(T, K)                                                          \
    do {                                                                     \
        const int _ip = (K) * PHI;                                           \
        DMA16(gsl + _ip + (2 * wave) * 4,                                    \
              &lds[(T) * SLOTI + (2 * wave) * 256]);                         \
        DMA16(gsl + _ip + (2 * wave + 1) * 4,                                \
              &lds[(T) * SLOTI + (2 * wave + 1) * 256]);                     \
        DMA16(ggl + _ip + (2 * wave) * 4,                                    \
              &lds[(T) * SLOTI + 2048 + (2 * wave) * 256]);                  \
        DMA16(ggl + _ip + (2 * wave + 1) * 4,                                \
              &lds[(T) * SLOTI + 2048 + (2 * wave + 1) * 256]);              \
    } while (0)

    // compute mapping: lane -> (row 16*wave + (lane&15), batches 2p, 2p+1)
    const int m = lane & 15;
    const int p = lane >> 4;
    const int wrow = 16 * wave + m;
    const uint32_t ldsb = (uint32_t)(uintptr_t)(las_t)&lds[0];
    const uint32_t wb   = ldsb + (uint32_t)(wrow * 16);
    const uint32_t xbas = ldsb + XOFFB + (uint32_t)(2 * p) * (XROW * 4);

    float acc0 = 0.0f, acc1 = 0.0f;

    // prologue: phases 0,1 in flight (8 outstanding DMAs per wave)
    ISSUE(0, 0);
    ISSUE(1, 1);
    SBAR();

    int cur = 0, iss = 2;
#pragma unroll 1
    for (int k = 0; k < NPH; ++k) {
        if (k < NPH - 1) VWAIT(4);      // retire phase k; k+1 stays in flight
        else             VWAIT(0);
        __builtin_amdgcn_s_barrier();   // raw barrier: no vmcnt(0) drain
        SBAR();
        if (k + 2 < NPH)
            ISSUE(iss, k + 2);          // refill reclaimed slot
        SBAR();

        {
            const uint32_t aw = wb + (uint32_t)cur * SLOTB;
            const uint32_t a0 = xbas + (uint32_t)k * 128u;
            const uint32_t a1 = a0 + (XROW * 4);
            i32x4 s0, s1, s2, s3, g0, g1, g2, g3;
            i32x4 xa0, xa1, xa2, xa3, xc0, xc1, xc2, xc3;

            // half A: j = 0..3
            DSR(s0, aw, 0);    DSR(s1, aw, 1024);
            DSR(s2, aw, 2048); DSR(s3, aw, 3072);
            DSR(g0, aw, 8192); DSR(g1, aw, 9216);
            DSR(g2, aw, 10240); DSR(g3, aw, 11264);
            DSR(xa0, a0, 0);  DSR(xa1, a0, 16);
            DSR(xa2, a0, 32); DSR(xa3, a0, 48);
            DSR(xc0, a1, 0);  DSR(xc1, a1, 16);
            DSR(xc2, a1, 32); DSR(xc3, a1, 48);
            LGKM0();
            STEP4(s0, g0, xa0, xc0); STEP4(s1, g1, xa1, xc1);
            STEP4(s2, g2, xa2, xc2); STEP4(s3, g3, xa3, xc3);

            // half B: j = 4..7
            DSR(s0, aw, 4096); DSR(s1, aw, 5120);
            DSR(s2, aw, 6144); DSR(s3, aw, 7168);
            DSR(g0, aw, 12288); DSR(g1, aw, 13312);
            DSR(g2, aw, 14336); DSR(g3, aw, 15360);
            DSR(xa0, a0, 64);  DSR(xa1, a0, 80);
            DSR(xa2, a0, 96);  DSR(xa3, a0, 112);
            DSR(xc0, a1, 64);  DSR(xc1, a1, 80);
            DSR(xc2, a1, 96);  DSR(xc3, a1, 112);
            LGKM0();
            STEP4(s0, g0, xa0, xc0); STEP4(s1, g1, xa1, xc1);
            STEP4(s2, g2, xa2, xc2); STEP4(s3, g3, xa3, xc3);
        }

        cur = (cur == NSLOT - 1) ? 0 : cur + 1;
        iss = (iss == NSLOT - 1) ? 0 : iss + 1;
    }

    // lane owns (row, 2 batches) fully for this slice: direct atomics
    {
        const int row = o0 + wrow;
        atomicAdd(out + (size_t)(2 * p) * OUT_F + row, acc0);
        atomicAdd(out + (size_t)(2 * p + 1) * OUT_F + row, acc1);
    }
#undef ISSUE
}

extern "C" void kernel_launch(void* const* d_in, const int* in_sizes, int n_in,
                              void* d_out, int out_size, void* d_ws, size_t ws_size,
                              hipStream_t stream)
{
    const float* x      = (const float*)d_in[0];
    const int*   stored = (const int*)d_in[1];
    const int*   sign   = (const int*)d_in[2];
    const float* lmin   = (const float*)d_in[3];
    const float* lmax   = (const float*)d_in[4];
    const float* bias   = (const float*)d_in[5];
    float* out = (float*)d_out;

    qins_init<<<dim3(OUT_F / 256), dim3(256), 0, stream>>>(bias, out);
    qins_main<<<dim3(RGRPS * NS), dim3(256), 0, stream>>>(
        x, stored, sign, lmin, lmax, out);
}

// Round 25
// 86.751 us; speedup vs baseline: 1.5134x; 1.0628x over previous
//
#include <hip/hip_runtime.h>
#include <stdint.h>

#define IN_F   4096
#define OUT_F  11008
#define BATCH  8
#define RPW    2                  // rows per wave (1 wave per block)
#define CHUNK  128                // i-values per chunk
#define NCHUNK (IN_F/CHUNK)       // 32
#define NSLOT  3                  // ring slots, 6 KB each -> 18 KB total
#define SLOTI  1536               // ints: stored[2][128] | sign[2][128] | x[8][128]
#define SLOTB  (SLOTI*4)          // 6144 B

typedef __attribute__((address_space(1))) const int* gas_t;
typedef __attribute__((address_space(3))) int* las_t;
typedef int i32x2 __attribute__((ext_vector_type(2)));

// async global->LDS DMA, 16 B/lane: no VGPR destination, regalloc-proof
#define DMA16(gsrc, ldst) \
    __builtin_amdgcn_global_load_lds((gas_t)(gsrc), (las_t)(ldst), 16, 0, 0)

#define SBAR() __builtin_amdgcn_sched_barrier(0)
#define VWAIT(N)                                                             \
    do {                                                                     \
        asm volatile("s_waitcnt vmcnt(" #N ")" ::: "memory");                \
        SBAR();                                                              \
    } while (0)
// compiler-opaque LDS read (R18-proven: compiler cannot tie it to the DMAs,
// so it inserts NO vmcnt(0) drain; our counted VWAIT is the only gate)
#define DSREAD(dst, addr, OFF)                                               \
    asm volatile("ds_read_b64 %0, %1 offset:" #OFF : "=v"(dst) : "v"(addr))
#define LGKM0()                                                              \
    do {                                                                     \
        asm volatile("s_waitcnt lgkmcnt(0)" ::: "memory");                   \
        SBAR();                                                              \
    } while (0)

__device__ __forceinline__ float qins_decode(int code, int sgn, float d0, float d1) {
    // |w| = exp2(d0 + code*d1); sign bit straight from the int32 sign (+1 / -1)
    const float e = __builtin_amdgcn_exp2f(fmaf((float)code, d1, d0));
    const uint32_t m = ((uint32_t)sgn) & 0x80000000u;
    return __uint_as_float(__float_as_uint(e) ^ m);
}

// Barrier-free per-wave DMA ring: one wave per block, ring slots are
// wave-private, so slot-reuse safety is pure program order (slot k+2 != slot
// k mod 3; slot k-1's reads completed at its lgkmcnt(0)). No s_barrier in the
// loop -> the counted vmcnt(6) NEVER drains the 2-chunk prefetch; 12 DMAs
// stay in flight per wave continuously (8 waves/CU -> 96 outstanding/CU).
__global__ __launch_bounds__(64)
void qins_linear_kernel(const float* __restrict__ x,
                        const int* __restrict__ stored,
                        const int* __restrict__ sign,
                        const float* __restrict__ log_min,
                        const float* __restrict__ log_max,
                        const float* __restrict__ bias,
                        float* __restrict__ out)
{
    // slot (ints): [0,256) stored rows 0,1 | [256,512) sign | [512,1536) x b=0..7
    __shared__ int lds[NSLOT][SLOTI];

    const int lane = threadIdx.x;          // 64 threads = 1 wave
    const int o0   = blockIdx.x * RPW;

    const float lmin = log_min[0];
    const float lmax = log_max[0];
    const float L2E  = 1.44269504088896340736f;
    // log2(|w|) = d0 + code*d1
    const float d1 = -(lmax - lmin) * (L2E / 254.0f);
    const float d0 = (lmin + (lmax - lmin) * (255.0f / 254.0f)) * L2E;

    // DMA sources: lanes 0-31 -> row/batch "+0", lanes 32-63 -> "+1"
    const int sub = lane >> 5;
    const int i32 = (lane & 31) * 4;
    const int* gs  = stored + (size_t)(o0 + sub) * IN_F + i32;
    const int* gg  = sign   + (size_t)(o0 + sub) * IN_F + i32;
    const int* gx0 = (const int*)x + (size_t)(0 + sub) * IN_F + i32;
    const int* gx1 = (const int*)x + (size_t)(2 + sub) * IN_F + i32;
    const int* gx2 = (const int*)x + (size_t)(4 + sub) * IN_F + i32;
    const int* gx3 = (const int*)x + (size_t)(6 + sub) * IN_F + i32;

#define ISSUE(T, K)                                                         \
    do {                                                                    \
        const int _ip = (K) * CHUNK;                                        \
        DMA16(gs + _ip,  &lds[T][0]);                                       \
        DMA16(gg + _ip,  &lds[T][256]);                                     \
        DMA16(gx0 + _ip, &lds[T][512]);                                     \
        DMA16(gx1 + _ip, &lds[T][768]);                                     \
        DMA16(gx2 + _ip, &lds[T][1024]);                                    \
        DMA16(gx3 + _ip, &lds[T][1280]);                                    \
    } while (0)

    float acc[RPW][BATCH];
#pragma unroll
    for (int r = 0; r < RPW; ++r)
#pragma unroll
        for (int b = 0; b < BATCH; ++b) acc[r][b] = 0.0f;

    // per-lane LDS byte base: lane l covers ints 2l, 2l+1 of each 128-int row
    const uint32_t base = (uint32_t)(uintptr_t)(las_t)&lds[0][0]
                        + (uint32_t)(lane * 8);

    // prologue: chunks 0 and 1 in flight (12 outstanding DMAs)
    ISSUE(0, 0);
    ISSUE(1, 1);
    SBAR();

    int cur = 0, iss = 2;
#pragma unroll 1
    for (int k = 0; k < NCHUNK; ++k) {
        // retire exactly chunk k's 6 DMAs; chunk k+1's 6 stay in flight
        if (k < NCHUNK - 1) VWAIT(6);
        else                VWAIT(0);

        if (k + 2 < NCHUNK)
            ISSUE(iss, k + 2);          // refill reclaimed slot (wave-private)
        SBAR();

        // compute chunk k via compiler-opaque asm ds_reads
        {
            const uint32_t a = base + (uint32_t)cur * SLOTB;
            i32x2 c0, c1, g0, g1, xv[BATCH];
            DSREAD(c0, a, 0);        // stored row o0   (ints 2l,2l+1)
            DSREAD(c1, a, 512);      // stored row o0+1
            DSREAD(g0, a, 1024);     // sign row o0
            DSREAD(g1, a, 1536);     // sign row o0+1
            DSREAD(xv[0], a, 2048);  // x batch 0
            DSREAD(xv[1], a, 2560);
            DSREAD(xv[2], a, 3072);
            DSREAD(xv[3], a, 3584);
            DSREAD(xv[4], a, 4096);
            DSREAD(xv[5], a, 4608);
            DSREAD(xv[6], a, 5120);
            DSREAD(xv[7], a, 5632);
            LGKM0();                 // rule #18 fence

            const float w00 = qins_decode(c0.x, g0.x, d0, d1);
            const float w01 = qins_decode(c0.y, g0.y, d0, d1);
            const float w10 = qins_decode(c1.x, g1.x, d0, d1);
            const float w11 = qins_decode(c1.y, g1.y, d0, d1);
#pragma unroll
            for (int b = 0; b < BATCH; ++b) {
                const float xlo = __int_as_float(xv[b].x);
                const float xhi = __int_as_float(xv[b].y);
                acc[0][b] = fmaf(w01, xhi, fmaf(w00, xlo, acc[0][b]));
                acc[1][b] = fmaf(w11, xhi, fmaf(w10, xlo, acc[1][b]));
            }
        }

        cur = (cur == NSLOT - 1) ? 0 : cur + 1;
        iss = (iss == NSLOT - 1) ? 0 : iss + 1;
    }

    // butterfly reduction of the 16 (row,batch) partials across the wave
#pragma unroll
    for (int r = 0; r < RPW; ++r)
#pragma unroll
        for (int b = 0; b < BATCH; ++b) {
            float v = acc[r][b];
#pragma unroll
            for (int s = 32; s >= 1; s >>= 1)
                v += __shfl_xor(v, s, 64);
            acc[r][b] = v;
        }

    if (lane == 0) {
#pragma unroll
        for (int r = 0; r < RPW; ++r) {
            const float bv = bias[o0 + r];
#pragma unroll
            for (int b = 0; b < BATCH; ++b)
                out[(size_t)b * OUT_F + o0 + r] = acc[r][b] + bv;
        }
    }
#undef ISSUE
}

extern "C" void kernel_launch(void* const* d_in, const int* in_sizes, int n_in,
                              void* d_out, int out_size, void* d_ws, size_t ws_size,
                              hipStream_t stream)
{
    const float* x      = (const float*)d_in[0];
    const int*   stored = (const int*)d_in[1];
    const int*   sign   = (const int*)d_in[2];
    const float* lmin   = (const float*)d_in[3];
    const float* lmax   = (const float*)d_in[4];
    const float* bias   = (const float*)d_in[5];
    float* out = (float*)d_out;

    dim3 grid(OUT_F / RPW), block(64);
    qins_linear_kernel<<<grid, block, 0, stream>>>(x, stored, sign, lmin, lmax, bias, out);
}

// Round 26
// 81.193 us; speedup vs baseline: 1.6169x; 1.0684x over previous
//
#include <hip/hip_runtime.h>
#include <stdint.h>

#define IN_F   4096
#define OUT_F  11008
#define BATCH  8
#define WAVES  2
#define RPW    4                  // rows per wave
#define RPB    (WAVES*RPW)        // 8 rows per block
#define CHUNK  128                // i-values per chunk
#define NCHUNK (IN_F/CHUNK)       // 32
#define NSLOT  3                  // weight ring slots, 8 KB each -> 24 KB
#define SLOTI  (2*RPB*CHUNK)      // 2048 ints per slot (stored | sign)
#define SLOTB  (SLOTI*4)          // 8192 B

typedef __attribute__((address_space(1))) const int* gas_t;
typedef __attribute__((address_space(3))) int* las_t;
typedef int i32x2 __attribute__((ext_vector_type(2)));

// async global->LDS DMA, 16 B/lane: no VGPR destination, regalloc-proof
#define DMA16(gsrc, ldst) \
    __builtin_amdgcn_global_load_lds((gas_t)(gsrc), (las_t)(ldst), 16, 0, 0)

#define SBAR() __builtin_amdgcn_sched_barrier(0)
#define VWAIT(N)                                                             \
    do {                                                                     \
        asm volatile("s_waitcnt vmcnt(" #N ")" ::: "memory");                \
        SBAR();                                                              \
    } while (0)
// compiler-opaque LDS read (R18-proven: compiler can't tie it to the DMAs,
// so no auto vmcnt(0) drain; landing is guaranteed by the x-use counted wait)
#define DSREAD(dst, addr, OFF)                                               \
    asm volatile("ds_read_b64 %0, %1 offset:" #OFF : "=v"(dst) : "v"(addr))
#define LGKM0()                                                              \
    do {                                                                     \
        asm volatile("s_waitcnt lgkmcnt(0)" ::: "memory");                   \
        SBAR();                                                              \
    } while (0)

__device__ __forceinline__ float qins_decode(int code, int sgn, float d0, float d1) {
    // |w| = exp2(d0 + code*d1); sign bit straight from the int32 sign (+1 / -1)
    const float e = __builtin_amdgcn_exp2f(fmaf((float)code, d1, d0));
    const uint32_t m = ((uint32_t)sgn) & 0x80000000u;
    return __uint_as_float(__float_as_uint(e) ^ m);
}

// Barrier-free weights-only DMA ring + x in registers:
//  - ring slots have WAVE-PRIVATE segments (each wave DMAs and reads only its
//    own 4 rows) -> no s_barrier in the loop, no coupled drains.
//  - x loaded per chunk as float2 from global (L1/L2-hot, issued BEFORE the
//    refill DMAs): the compiler's counted wait at x-use (vmcnt(4)) retires
//    x + chunk k+1's weights while chunk k+2's DMAs stay in flight.
__global__ __launch_bounds__(WAVES*64)
void qins_linear_kernel(const float* __restrict__ x,
                        const int* __restrict__ stored,
                        const int* __restrict__ sign,
                        const float* __restrict__ log_min,
                        const float* __restrict__ log_max,
                        const float* __restrict__ bias,
                        float* __restrict__ out)
{
    // slot t, wave w segment [w*1024, w*1024+1024) ints:
    //   stored rows 0..3 at +0 (row r at byte r*512), sign at +512 ints
    __shared__ int lds[NSLOT][SLOTI];

    const int tid  = threadIdx.x;
    const int lane = tid & 63;
    const int wave = tid >> 6;
    const int o0   = blockIdx.x * RPB;
    const int r0   = o0 + wave * RPW;      // this wave's first row

    const float lmin = log_min[0];
    const float lmax = log_max[0];
    const float L2E  = 1.44269504088896340736f;
    // log2(|w|) = d0 + code*d1
    const float d1 = -(lmax - lmin) * (L2E / 254.0f);
    const float d0 = (lmin + (lmax - lmin) * (255.0f / 254.0f)) * L2E;

    // DMA sources: one DMA16 covers a row PAIR (lanes 0-31 -> first row,
    // lanes 32-63 -> second row), 128 ints each
    const int sub = lane >> 5;
    const int i32 = (lane & 31) * 4;
    const int* gsA = stored + (size_t)(r0 + sub) * IN_F + i32;       // rows 0,1
    const int* gsB = gsA + 2 * IN_F;                                 // rows 2,3
    const int* ggA = sign   + (size_t)(r0 + sub) * IN_F + i32;
    const int* ggB = ggA + 2 * IN_F;

#define ISSUE(T, K)                                                          \
    do {                                                                     \
        const int _ip = (K) * CHUNK;                                         \
        DMA16(gsA + _ip, &lds[T][wave * 1024]);                              \
        DMA16(gsB + _ip, &lds[T][wave * 1024 + 256]);                        \
        DMA16(ggA + _ip, &lds[T][wave * 1024 + 512]);                        \
        DMA16(ggB + _ip, &lds[T][wave * 1024 + 768]);                        \
    } while (0)

    float acc[RPW][BATCH];
#pragma unroll
    for (int r = 0; r < RPW; ++r)
#pragma unroll
        for (int b = 0; b < BATCH; ++b) acc[r][b] = 0.0f;

    // per-lane LDS byte base: lane covers ints 2l, 2l+1 of each 128-int row
    const uint32_t base = (uint32_t)(uintptr_t)(las_t)&lds[0][0]
                        + (uint32_t)(wave * 4096 + lane * 8);

    // prologue: weight chunks 0,1 in flight (8 outstanding DMAs per wave)
    ISSUE(0, 0);
    ISSUE(1, 1);
    SBAR();

    int cur = 0, iss = 2;
#pragma unroll 1
    for (int k = 0; k < NCHUNK; ++k) {
        // x(k): plain loads, issued BEFORE the refill DMAs (FIFO position!)
        float2 xv[BATCH];
#pragma unroll
        for (int b = 0; b < BATCH; ++b)
            xv[b] = *reinterpret_cast<const float2*>(
                x + b * IN_F + k * CHUNK + 2 * lane);
        SBAR();

        if (k + 2 < NCHUNK)
            ISSUE(iss, k + 2);          // refill reclaimed wave-private slot
        SBAR();

        // guarantee chunk k's weights landed (no-op in steady state:
        // exactly [w(k+1)x4, x(k)x8, w(k+2)x4] = 16 outstanding here)
        VWAIT(16);

        // weights chunk k via compiler-opaque ds_reads
        {
            const uint32_t a = base + (uint32_t)cur * SLOTB;
            i32x2 c0, c1, c2, c3, g0, g1, g2, g3;
            DSREAD(c0, a, 0);        // stored row r0+0, ints 2l,2l+1
            DSREAD(c1, a, 512);
            DSREAD(c2, a, 1024);
            DSREAD(c3, a, 1536);
            DSREAD(g0, a, 2048);     // sign rows
            DSREAD(g1, a, 2560);
            DSREAD(g2, a, 3072);
            DSREAD(g3, a, 3584);
            LGKM0();                 // rule #18 fence

            float wlo[RPW], whi[RPW];
            wlo[0] = qins_decode(c0.x, g0.x, d0, d1);
            whi[0] = qins_decode(c0.y, g0.y, d0, d1);
            wlo[1] = qins_decode(c1.x, g1.x, d0, d1);
            whi[1] = qins_decode(c1.y, g1.y, d0, d1);
            wlo[2] = qins_decode(c2.x, g2.x, d0, d1);
            whi[2] = qins_decode(c2.y, g2.y, d0, d1);
            wlo[3] = qins_decode(c3.x, g3.x, d0, d1);
            whi[3] = qins_decode(c3.y, g3.y, d0, d1);

            // compiler inserts its counted vmcnt before first xv use:
            // younger-than-x = the 4 refill DMAs -> vmcnt(4), k+2 stays in flight
#pragma unroll
            for (int b = 0; b < BATCH; ++b) {
                const float xlo = xv[b].x;
                const float xhi = xv[b].y;
#pragma unroll
                for (int r = 0; r < RPW; ++r)
                    acc[r][b] = fmaf(whi[r], xhi,
                                fmaf(wlo[r], xlo, acc[r][b]));
            }
        }

        cur = (cur == NSLOT - 1) ? 0 : cur + 1;
        iss = (iss == NSLOT - 1) ? 0 : iss + 1;
    }

    // butterfly reduction of the 32 (row,batch) partials across the wave
#pragma unroll
    for (int r = 0; r < RPW; ++r)
#pragma unroll
        for (int b = 0; b < BATCH; ++b) {
            float v = acc[r][b];
#pragma unroll
            for (int s = 32; s >= 1; s >>= 1)
                v += __shfl_xor(v, s, 64);
            acc[r][b] = v;
        }

    if (lane == 0) {
#pragma unroll
        for (int r = 0; r < RPW; ++r) {
            const int row = r0 + r;
            const float bv = bias[row];
#pragma unroll
            for (int b = 0; b < BATCH; ++b)
                out[(size_t)b * OUT_F + row] = acc[r][b] + bv;
        }
    }
#undef ISSUE
}

extern "C" void kernel_launch(void* const* d_in, const int* in_sizes, int n_in,
                              void* d_out, int out_size, void* d_ws, size_t ws_size,
                              hipStream_t stream)
{
    const float* x      = (const float*)d_in[0];
    const int*   stored = (const int*)d_in[1];
    const int*   sign   = (const int*)d_in[2];
    const float* lmin   = (const float*)d_in[3];
    const float* lmax   = (const float*)d_in[4];
    const float* bias   = (const float*)d_in[5];
    float* out = (float*)d_out;

    dim3 grid(OUT_F / RPB), block(WAVES * 64);
    qins_linear_kernel<<<grid, block, 0, stream>>>(x, stored, sign, lmin, lmax, bias, out);
}